// Round 2
// baseline (1055.211 us; speedup 1.0000x reference)
//
#include <hip/hip_runtime.h>

// ---------------------------------------------------------------------------
// BertAttention (relative_key_query) on MI355X. FP32 I/O, bf16 MFMA compute.
// B=8 S=1024 E=1024 H=16 D=64 M=1024
// Pipeline: 3x QKV GEMM (fp32 in -> bf16 out) -> fused flash attention w/
// MFMA rel-bias -> out-proj GEMM (+bias+residual, fp32 out) -> LayerNorm.
// ---------------------------------------------------------------------------

typedef unsigned short u16;
typedef __bf16 bf16x8 __attribute__((ext_vector_type(8)));
typedef float  f32x4  __attribute__((ext_vector_type(4)));
typedef int    i32x4  __attribute__((ext_vector_type(4)));

__device__ __forceinline__ float b2f(u16 u) {
  union { unsigned int i; float f; } x;
  x.i = ((unsigned int)u) << 16;
  return x.f;
}
__device__ __forceinline__ u16 f2b(float f) {
  union { float f; unsigned int u; } x;
  x.f = f;
  unsigned int r = (x.u + 0x7FFFu + ((x.u >> 16) & 1u)) >> 16;
  return (u16)r;
}
union LdU { i32x4 i4; bf16x8 b8; };
__device__ __forceinline__ bf16x8 ldb8(const u16* p) {
  LdU u; u.i4 = *(const i32x4*)p; return u.b8;
}
__device__ __forceinline__ void pack8(u16* dst, f32x4 lo, f32x4 hi) {
  u16 t[8] __attribute__((aligned(16)));
  t[0] = f2b(lo.x); t[1] = f2b(lo.y); t[2] = f2b(lo.z); t[3] = f2b(lo.w);
  t[4] = f2b(hi.x); t[5] = f2b(hi.y); t[6] = f2b(hi.z); t[7] = f2b(hi.w);
  *(i32x4*)dst = *(i32x4*)t;
}
#define MFMA16(a, b, c) __builtin_amdgcn_mfma_f32_16x16x32_bf16((a), (b), (c), 0, 0, 0)

// ---------------------------------------------------------------------------
// GEMM: out[N,M] = A[N,K] @ W[K,M] + bias (+ residual). 64x64 block tile,
// 4 waves, each wave a 16x64 strip of 16x16x32 MFMAs. W staged transposed in
// LDS with XOR column-group swizzle (conflict-free transpose writes).
// AF32: A is fp32 (convert to bf16 on staging); else A is bf16 u16.
// ---------------------------------------------------------------------------
template <int AF32, int RESID, int OUTF32>
__global__ __launch_bounds__(256) void gemm64(
    const void* __restrict__ Ap, const float* __restrict__ W,
    const float* __restrict__ bias, const float* __restrict__ resid,
    float* __restrict__ outF, u16* __restrict__ outB, int N, int K, int M) {
  __shared__ u16 sA[64][72];  // +8 pad: 144B row stride
  __shared__ u16 sW[64][72];  // Wt[n][k'], column-group swizzled

  const int tid = threadIdx.x;
  const int lane = tid & 63, w = tid >> 6;
  const int quad = lane >> 4, lb = lane & 15;
  const int m0 = blockIdx.x * 64, n0 = blockIdx.y * 64;

  f32x4 acc[4] = {};

  for (int k0 = 0; k0 < K; k0 += 64) {
    // stage A tile (8 elems/chunk, coalesced)
#pragma unroll
    for (int ch = tid; ch < 512; ch += 256) {
      int r = ch >> 3, c8 = (ch & 7) << 3;
      if (AF32) {
        const float* src = (const float*)Ap + (size_t)(n0 + r) * K + k0 + c8;
        pack8(&sA[r][c8], *(const f32x4*)src, *(const f32x4*)(src + 4));
      } else {
        const u16* src = (const u16*)Ap + (size_t)(n0 + r) * K + k0 + c8;
        *(i32x4*)&sA[r][c8] = *(const i32x4*)src;
      }
    }
    // stage W transposed: sW[n][col'] where col'-group = (k>>3) ^ (n>>3)
#pragma unroll
    for (int ch = tid; ch < 512; ch += 256) {
      int k = ch >> 3, a = ch & 7;  // a = n-group
      const float* src = W + (size_t)(k0 + k) * M + m0 + a * 8;
      f32x4 lo = *(const f32x4*)src, hi = *(const f32x4*)(src + 4);
      int colbase = ((((k >> 3) ^ a) << 3) | (k & 7));
      sW[a * 8 + 0][colbase] = f2b(lo.x);
      sW[a * 8 + 1][colbase] = f2b(lo.y);
      sW[a * 8 + 2][colbase] = f2b(lo.z);
      sW[a * 8 + 3][colbase] = f2b(lo.w);
      sW[a * 8 + 4][colbase] = f2b(hi.x);
      sW[a * 8 + 5][colbase] = f2b(hi.y);
      sW[a * 8 + 6][colbase] = f2b(hi.z);
      sW[a * 8 + 7][colbase] = f2b(hi.w);
    }
    __syncthreads();

    const int row = 16 * w + lb;
    bf16x8 a0 = ldb8(&sA[row][quad * 8]);
    bf16x8 a1 = ldb8(&sA[row][32 + quad * 8]);
#pragma unroll
    for (int t = 0; t < 4; t++) {
      int n = 16 * t + lb;
      int sw = (n >> 3) & 7;
      bf16x8 b0 = ldb8(&sW[n][(quad ^ sw) << 3]);
      bf16x8 b1 = ldb8(&sW[n][((4 + quad) ^ sw) << 3]);
      acc[t] = MFMA16(a0, b0, acc[t]);
      acc[t] = MFMA16(a1, b1, acc[t]);
    }
    __syncthreads();
  }

#pragma unroll
  for (int t = 0; t < 4; t++) {
    int col = m0 + 16 * t + lb;
    float bv = bias[col];
#pragma unroll
    for (int i = 0; i < 4; i++) {
      int rowg = n0 + 16 * w + quad * 4 + i;
      float v = acc[t][i] + bv;
      if (RESID) v += resid[(size_t)rowg * M + col];
      if (OUTF32) outF[(size_t)rowg * M + col] = v;
      else        outB[(size_t)rowg * M + col] = f2b(v);
    }
  }
}

// ---------------------------------------------------------------------------
// Fused attention: one block = (b, h, 64 q-rows). Online softmax over 16
// k-tiles of 64. Rel bias via MFMA: Gq = Qt @ Pwin^T, Gk = Kt @ Pwin^T
// ([64 x 127-delta-window]) then LDS gather Gq[rl][rl-cl+63] + Gk[cl][..].
// Q/K/V/ctx are bf16 workspace; dist_emb is fp32 (converted at staging).
// ---------------------------------------------------------------------------
__global__ __launch_bounds__(256) void attn(
    const u16* __restrict__ Q, const u16* __restrict__ Kv,
    const u16* __restrict__ V, const float* __restrict__ dist,
    u16* __restrict__ ctx) {
  __shared__ u16 sQ[64][72];
  __shared__ u16 sK[64][72];
  __shared__ u16 sVt[64][72];   // V^T [d][r'], swizzled
  __shared__ u16 sPr[64][72];   // probs bf16
  __shared__ u16 sP[128][72];   // dist_emb window [delta][d]
  __shared__ u16 sGq[64][136];  // bf16 G matrices
  __shared__ u16 sGk[64][136];

  const int tid = threadIdx.x;
  const int lane = tid & 63, w = tid >> 6;
  const int quad = lane >> 4, lb = lane & 15;
  const int bh = blockIdx.y, b = bh >> 4, h = bh & 15;
  const int q0 = blockIdx.x << 6;
  const int S = 1024, E = 1024;
  const u16* Qb = Q  + (size_t)(b * S) * E + h * 64;
  const u16* Kb = Kv + (size_t)(b * S) * E + h * 64;
  const u16* Vb = V  + (size_t)(b * S) * E + h * 64;

  // stage Q tile once
  for (int ch = tid; ch < 512; ch += 256) {
    int r = ch >> 3, c8 = (ch & 7) << 3;
    *(i32x4*)&sQ[r][c8] = *(const i32x4*)&Qb[(size_t)(q0 + r) * E + c8];
  }
  __syncthreads();

  const int row = 16 * w + lb;
  bf16x8 aq0 = ldb8(&sQ[row][quad * 8]);
  bf16x8 aq1 = ldb8(&sQ[row][32 + quad * 8]);

  f32x4 accO[4] = {};
  float m_i[4], l_i[4];
#pragma unroll
  for (int i = 0; i < 4; i++) { m_i[i] = -3.0e38f; l_i[i] = 0.f; }

  for (int kt = 0; kt < 16; kt++) {
    const int r0 = kt << 6;
    // stage K tile
    for (int ch = tid; ch < 512; ch += 256) {
      int r = ch >> 3, c8 = (ch & 7) << 3;
      *(i32x4*)&sK[r][c8] = *(const i32x4*)&Kb[(size_t)(r0 + r) * E + c8];
    }
    // stage V transposed (swizzled)
    for (int ch = tid; ch < 512; ch += 256) {
      int r = ch >> 3, a = ch & 7;  // a = d-group
      i32x4 v = *(const i32x4*)&Vb[(size_t)(r0 + r) * E + a * 8];
      u16 tmp[8] __attribute__((aligned(16)));
      *(i32x4*)tmp = v;
      int colbase = ((((r >> 3) ^ a) << 3) | (r & 7));
#pragma unroll
      for (int j = 0; j < 8; j++) sVt[a * 8 + j][colbase] = tmp[j];
    }
    // stage dist_emb window (fp32 -> bf16): sP[p] = dist[q0-r0+960 + p]
    const int dbase = q0 - r0 + 960;
    for (int ch = tid; ch < 1024; ch += 256) {
      int p = ch >> 3, c8 = (ch & 7) << 3;
      int g = dbase + p;
      if (g > 2046) g = 2046;  // pad row 127, never gathered
      const float* src = dist + (size_t)g * 64 + c8;
      pack8(&sP[p][c8], *(const f32x4*)src, *(const f32x4*)(src + 4));
    }
    __syncthreads();

    // --- QK^T ---
    f32x4 accS[4] = {};
#pragma unroll
    for (int t = 0; t < 4; t++) {
      int n = 16 * t + lb;
      bf16x8 b0 = ldb8(&sK[n][quad * 8]);
      bf16x8 b1 = ldb8(&sK[n][32 + quad * 8]);
      accS[t] = MFMA16(aq0, b0, accS[t]);
      accS[t] = MFMA16(aq1, b1, accS[t]);
    }
    // --- Gq, Gk (rel bias GEMMs) ---
    bf16x8 ak0 = ldb8(&sK[row][quad * 8]);
    bf16x8 ak1 = ldb8(&sK[row][32 + quad * 8]);
#pragma unroll
    for (int u = 0; u < 8; u++) {
      int n = 16 * u + lb;
      bf16x8 p0 = ldb8(&sP[n][quad * 8]);
      bf16x8 p1 = ldb8(&sP[n][32 + quad * 8]);
      f32x4 gq = {}, gk = {};
      gq = MFMA16(aq0, p0, gq); gq = MFMA16(aq1, p1, gq);
      gk = MFMA16(ak0, p0, gk); gk = MFMA16(ak1, p1, gk);
#pragma unroll
      for (int i = 0; i < 4; i++) {
        sGq[16 * w + quad * 4 + i][16 * u + lb] = f2b(gq[i]);
        sGk[16 * w + quad * 4 + i][16 * u + lb] = f2b(gk[i]);
      }
    }
    __syncthreads();

    // --- bias gather + scale + online softmax ---
    float pr[4][4], rmax[4], rsum[4], alpha[4];
#pragma unroll
    for (int i = 0; i < 4; i++) rmax[i] = -3.0e38f;
#pragma unroll
    for (int t = 0; t < 4; t++) {
#pragma unroll
      for (int i = 0; i < 4; i++) {
        int rl = 16 * w + quad * 4 + i;  // local q row
        int cl = 16 * t + lb;            // local k col
        int c = rl - cl + 63;            // delta window col, 0..126
        float s = (accS[t][i] + b2f(sGq[rl][c]) + b2f(sGk[cl][c])) * 0.125f;
        pr[t][i] = s;
        rmax[i] = fmaxf(rmax[i], s);
      }
    }
#pragma unroll
    for (int d = 1; d < 16; d <<= 1)
#pragma unroll
      for (int i = 0; i < 4; i++)
        rmax[i] = fmaxf(rmax[i], __shfl_xor(rmax[i], d, 64));
#pragma unroll
    for (int i = 0; i < 4; i++) {
      float mn = fmaxf(m_i[i], rmax[i]);
      alpha[i] = __expf(m_i[i] - mn);
      m_i[i] = mn;
      rsum[i] = 0.f;
    }
#pragma unroll
    for (int t = 0; t < 4; t++)
#pragma unroll
      for (int i = 0; i < 4; i++) {
        float e = __expf(pr[t][i] - m_i[i]);
        pr[t][i] = e;
        rsum[i] += e;
      }
#pragma unroll
    for (int d = 1; d < 16; d <<= 1)
#pragma unroll
      for (int i = 0; i < 4; i++)
        rsum[i] += __shfl_xor(rsum[i], d, 64);
#pragma unroll
    for (int i = 0; i < 4; i++) l_i[i] = l_i[i] * alpha[i] + rsum[i];

    // write probs (bf16) for PV A-operand
#pragma unroll
    for (int t = 0; t < 4; t++)
#pragma unroll
      for (int i = 0; i < 4; i++)
        sPr[16 * w + quad * 4 + i][16 * t + lb] = f2b(pr[t][i]);
    // rescale running context
#pragma unroll
    for (int t = 0; t < 4; t++)
#pragma unroll
      for (int i = 0; i < 4; i++) accO[t][i] *= alpha[i];
    __syncthreads();

    // --- PV ---
    bf16x8 ap0 = ldb8(&sPr[row][quad * 8]);
    bf16x8 ap1 = ldb8(&sPr[row][32 + quad * 8]);
#pragma unroll
    for (int t = 0; t < 4; t++) {
      int n = 16 * t + lb;
      int sw = (n >> 3) & 7;
      bf16x8 v0 = ldb8(&sVt[n][(quad ^ sw) << 3]);
      bf16x8 v1 = ldb8(&sVt[n][((4 + quad) ^ sw) << 3]);
      accO[t] = MFMA16(ap0, v0, accO[t]);
      accO[t] = MFMA16(ap1, v1, accO[t]);
    }
    __syncthreads();
  }

  // epilogue: ctx = accO / l
  u16* Cb = ctx + (size_t)(b * S) * E + h * 64;
#pragma unroll
  for (int t = 0; t < 4; t++)
#pragma unroll
    for (int i = 0; i < 4; i++) {
      int rl = 16 * w + quad * 4 + i;
      Cb[(size_t)(q0 + rl) * E + 16 * t + lb] = f2b(accO[t][i] / l_i[i]);
    }
}

// ---------------------------------------------------------------------------
// Row LayerNorm: fp32 in [8192,1024], fp32 out.
// ---------------------------------------------------------------------------
__global__ __launch_bounds__(256) void lnorm(
    const float* __restrict__ Hp, const float* __restrict__ gamma,
    const float* __restrict__ beta, float* __restrict__ out) {
  __shared__ float red[8];
  const int rowb = blockIdx.x, tid = threadIdx.x;
  const float* hr = Hp + (size_t)rowb * 1024;
  f32x4 v = *(const f32x4*)&hr[tid * 4];
  float s = v.x + v.y + v.z + v.w;
  float q = v.x * v.x + v.y * v.y + v.z * v.z + v.w * v.w;
#pragma unroll
  for (int d = 1; d < 64; d <<= 1) {
    s += __shfl_xor(s, d, 64);
    q += __shfl_xor(q, d, 64);
  }
  int w = tid >> 6, lane = tid & 63;
  if (lane == 0) { red[w] = s; red[4 + w] = q; }
  __syncthreads();
  s = red[0] + red[1] + red[2] + red[3];
  q = red[4] + red[5] + red[6] + red[7];
  float mu = s * (1.f / 1024.f);
  float var = q * (1.f / 1024.f) - mu * mu;
  float rstd = rsqrtf(var + 1e-12f);
  float* orow = out + (size_t)rowb * 1024;
  f32x4 o;
#pragma unroll
  for (int j = 0; j < 4; j++) {
    int c = tid * 4 + j;
    o[j] = (v[j] - mu) * rstd * gamma[c] + beta[c];
  }
  *(f32x4*)&orow[tid * 4] = o;
}

// ---------------------------------------------------------------------------
extern "C" void kernel_launch(void* const* d_in, const int* in_sizes, int n_in,
                              void* d_out, int out_size, void* d_ws,
                              size_t ws_size, hipStream_t stream) {
  const float* X    = (const float*)d_in[0];
  const float* Wq   = (const float*)d_in[1];
  const float* bq   = (const float*)d_in[2];
  const float* Wk   = (const float*)d_in[3];
  const float* bk   = (const float*)d_in[4];
  const float* Wv   = (const float*)d_in[5];
  const float* bv   = (const float*)d_in[6];
  const float* dist = (const float*)d_in[7];
  const float* Wo   = (const float*)d_in[8];
  const float* bo   = (const float*)d_in[9];
  const float* gam  = (const float*)d_in[10];
  const float* bet  = (const float*)d_in[11];

  const size_t NE = (size_t)8192 * 1024;  // elements per [B*S, E] tensor
  char* ws = (char*)d_ws;
  u16* Qw = (u16*)(ws);                // bf16 [0, 2NE)
  u16* Kw = (u16*)(ws + 2 * NE);       // bf16 [2NE, 4NE)
  u16* Vw = (u16*)(ws + 4 * NE);       // bf16 [4NE, 6NE)
  u16* Cw = (u16*)(ws + 6 * NE);       // bf16 [6NE, 8NE)   (64 MB total)
  float* Hp = (float*)ws;              // fp32 pre-LN, overlays dead Q+K

  dim3 bb(256);
  dim3 gg(16, 128);
  gemm64<1, 0, 0><<<gg, bb, 0, stream>>>(X, Wq, bq, nullptr, nullptr, Qw, 8192, 1024, 1024);
  gemm64<1, 0, 0><<<gg, bb, 0, stream>>>(X, Wk, bk, nullptr, nullptr, Kw, 8192, 1024, 1024);
  gemm64<1, 0, 0><<<gg, bb, 0, stream>>>(X, Wv, bv, nullptr, nullptr, Vw, 8192, 1024, 1024);
  attn<<<dim3(16, 128), bb, 0, stream>>>(Qw, Kw, Vw, dist, Cw);
  gemm64<0, 1, 1><<<gg, bb, 0, stream>>>(Cw, Wo, bo, X, Hp, nullptr, 8192, 1024, 1024);
  lnorm<<<dim3(8192), bb, 0, stream>>>(Hp, gam, bet, (float*)d_out);
}

// Round 3
// 753.396 us; speedup vs baseline: 1.4006x; 1.4006x over previous
//
#include <hip/hip_runtime.h>

// ---------------------------------------------------------------------------
// BertAttention (relative_key_query) on MI355X. FP32 I/O, bf16 MFMA compute.
// B=8 S=1024 E=1024 H=16 D=64 M=1024
// R3: attn LDS 88->79KB (2 blocks/CU) + 3 barriers/ktile; GEMM 128x64 tiles.
// ---------------------------------------------------------------------------

typedef unsigned short u16;
typedef __bf16 bf16x8 __attribute__((ext_vector_type(8)));
typedef float  f32x4  __attribute__((ext_vector_type(4)));
typedef int    i32x4  __attribute__((ext_vector_type(4)));

__device__ __forceinline__ float b2f(u16 u) {
  union { unsigned int i; float f; } x;
  x.i = ((unsigned int)u) << 16;
  return x.f;
}
__device__ __forceinline__ u16 f2b(float f) {
  union { float f; unsigned int u; } x;
  x.f = f;
  unsigned int r = (x.u + 0x7FFFu + ((x.u >> 16) & 1u)) >> 16;
  return (u16)r;
}
union LdU { i32x4 i4; bf16x8 b8; };
__device__ __forceinline__ bf16x8 ldb8(const u16* p) {
  LdU u; u.i4 = *(const i32x4*)p; return u.b8;
}
__device__ __forceinline__ void pack8(u16* dst, f32x4 lo, f32x4 hi) {
  u16 t[8] __attribute__((aligned(16)));
  t[0] = f2b(lo.x); t[1] = f2b(lo.y); t[2] = f2b(lo.z); t[3] = f2b(lo.w);
  t[4] = f2b(hi.x); t[5] = f2b(hi.y); t[6] = f2b(hi.z); t[7] = f2b(hi.w);
  *(i32x4*)dst = *(i32x4*)t;
}
#define MFMA16(a, b, c) __builtin_amdgcn_mfma_f32_16x16x32_bf16((a), (b), (c), 0, 0, 0)

// ---------------------------------------------------------------------------
// GEMM: out[N,M] = A[N,K] @ W[K,M] + bias (+ residual). 128x64 block tile,
// 4 waves, each wave a 32x64 strip (two 16-row MFMA tiles). W staged
// transposed in LDS with XOR column-group swizzle.
// AF32: A is fp32 (convert to bf16 on staging); else A is bf16 u16.
// ---------------------------------------------------------------------------
template <int AF32, int RESID, int OUTF32>
__global__ __launch_bounds__(256) void gemm128(
    const void* __restrict__ Ap, const float* __restrict__ W,
    const float* __restrict__ bias, const float* __restrict__ resid,
    float* __restrict__ outF, u16* __restrict__ outB, int N, int K, int M) {
  __shared__ u16 sA[128][72];  // +8 pad: 144B row stride
  __shared__ u16 sW[64][72];   // Wt[n][k'], column-group swizzled

  const int tid = threadIdx.x;
  const int lane = tid & 63, w = tid >> 6;
  const int quad = lane >> 4, lb = lane & 15;
  const int m0 = blockIdx.x * 64, n0 = blockIdx.y * 128;

  f32x4 acc[2][4] = {};

  for (int k0 = 0; k0 < K; k0 += 64) {
    // stage A tile (128x64, 8 elems/chunk, coalesced)
#pragma unroll
    for (int ch = tid; ch < 1024; ch += 256) {
      int r = ch >> 3, c8 = (ch & 7) << 3;
      if (AF32) {
        const float* src = (const float*)Ap + (size_t)(n0 + r) * K + k0 + c8;
        pack8(&sA[r][c8], *(const f32x4*)src, *(const f32x4*)(src + 4));
      } else {
        const u16* src = (const u16*)Ap + (size_t)(n0 + r) * K + k0 + c8;
        *(i32x4*)&sA[r][c8] = *(const i32x4*)src;
      }
    }
    // stage W transposed: sW[n][col'] where col'-group = (k>>3) ^ (n>>3)
#pragma unroll
    for (int ch = tid; ch < 512; ch += 256) {
      int k = ch >> 3, a = ch & 7;  // a = n-group
      const float* src = W + (size_t)(k0 + k) * M + m0 + a * 8;
      f32x4 lo = *(const f32x4*)src, hi = *(const f32x4*)(src + 4);
      int colbase = ((((k >> 3) ^ a) << 3) | (k & 7));
      sW[a * 8 + 0][colbase] = f2b(lo.x);
      sW[a * 8 + 1][colbase] = f2b(lo.y);
      sW[a * 8 + 2][colbase] = f2b(lo.z);
      sW[a * 8 + 3][colbase] = f2b(lo.w);
      sW[a * 8 + 4][colbase] = f2b(hi.x);
      sW[a * 8 + 5][colbase] = f2b(hi.y);
      sW[a * 8 + 6][colbase] = f2b(hi.z);
      sW[a * 8 + 7][colbase] = f2b(hi.w);
    }
    __syncthreads();

    const int r0 = 32 * w + lb;
    bf16x8 a00 = ldb8(&sA[r0][quad * 8]);
    bf16x8 a01 = ldb8(&sA[r0][32 + quad * 8]);
    bf16x8 a10 = ldb8(&sA[r0 + 16][quad * 8]);
    bf16x8 a11 = ldb8(&sA[r0 + 16][32 + quad * 8]);
#pragma unroll
    for (int t = 0; t < 4; t++) {
      int n = 16 * t + lb;
      int sw = (n >> 3) & 7;
      bf16x8 b0 = ldb8(&sW[n][(quad ^ sw) << 3]);
      bf16x8 b1 = ldb8(&sW[n][((4 + quad) ^ sw) << 3]);
      acc[0][t] = MFMA16(a00, b0, acc[0][t]);
      acc[0][t] = MFMA16(a01, b1, acc[0][t]);
      acc[1][t] = MFMA16(a10, b0, acc[1][t]);
      acc[1][t] = MFMA16(a11, b1, acc[1][t]);
    }
    __syncthreads();
  }

#pragma unroll
  for (int half = 0; half < 2; half++)
#pragma unroll
    for (int t = 0; t < 4; t++) {
      int col = m0 + 16 * t + lb;
      float bv = bias[col];
#pragma unroll
      for (int i = 0; i < 4; i++) {
        int rowg = n0 + 32 * w + 16 * half + quad * 4 + i;
        float v = acc[half][t][i] + bv;
        if (RESID) v += resid[(size_t)rowg * M + col];
        if (OUTF32) outF[(size_t)rowg * M + col] = v;
        else        outB[(size_t)rowg * M + col] = f2b(v);
      }
    }
}

// ---------------------------------------------------------------------------
// Fused attention: one block = (b, h, 64 q-rows). Online softmax over 16
// k-tiles of 64. Rel bias via MFMA: Gq = Qt @ Pwin^T, Gk = Kt @ Pwin^T
// ([64 x 127-delta-window]) then LDS gather Gq[rl][rl-cl+63] + Gk[cl][..].
// Probs overlay sGq (wave-private rows); 3 barriers/ktile; LDS 79 KB ->
// 2 blocks/CU.
// ---------------------------------------------------------------------------
__global__ __launch_bounds__(256) void attn(
    const u16* __restrict__ Q, const u16* __restrict__ Kv,
    const u16* __restrict__ V, const float* __restrict__ dist,
    u16* __restrict__ ctx) {
  __shared__ u16 sQ[64][72];
  __shared__ u16 sK[64][72];
  __shared__ u16 sVt[64][72];   // V^T [d][r'], swizzled
  __shared__ u16 sP[128][72];   // dist_emb window [delta][d]
  __shared__ u16 sGq[64][136];  // bf16 Gq; probs overlay cols [0,64)
  __shared__ u16 sGk[64][136];  // bf16 Gk

  const int tid = threadIdx.x;
  const int lane = tid & 63, w = tid >> 6;
  const int quad = lane >> 4, lb = lane & 15;
  const int bh = blockIdx.y, b = bh >> 4, h = bh & 15;
  const int q0 = blockIdx.x << 6;
  const int S = 1024, E = 1024;
  const u16* Qb = Q  + (size_t)(b * S) * E + h * 64;
  const u16* Kb = Kv + (size_t)(b * S) * E + h * 64;
  const u16* Vb = V  + (size_t)(b * S) * E + h * 64;

  // stage Q tile once
  for (int ch = tid; ch < 512; ch += 256) {
    int r = ch >> 3, c8 = (ch & 7) << 3;
    *(i32x4*)&sQ[r][c8] = *(const i32x4*)&Qb[(size_t)(q0 + r) * E + c8];
  }
  __syncthreads();

  const int row = 16 * w + lb;
  bf16x8 aq0 = ldb8(&sQ[row][quad * 8]);
  bf16x8 aq1 = ldb8(&sQ[row][32 + quad * 8]);

  f32x4 accO[4] = {};
  float m_i[4], l_i[4];
#pragma unroll
  for (int i = 0; i < 4; i++) { m_i[i] = -3.0e38f; l_i[i] = 0.f; }

  for (int kt = 0; kt < 16; kt++) {
    const int r0 = kt << 6;
    // stage K tile
    for (int ch = tid; ch < 512; ch += 256) {
      int r = ch >> 3, c8 = (ch & 7) << 3;
      *(i32x4*)&sK[r][c8] = *(const i32x4*)&Kb[(size_t)(r0 + r) * E + c8];
    }
    // stage V transposed (swizzled)
    for (int ch = tid; ch < 512; ch += 256) {
      int r = ch >> 3, a = ch & 7;  // a = d-group
      i32x4 v = *(const i32x4*)&Vb[(size_t)(r0 + r) * E + a * 8];
      u16 tmp[8] __attribute__((aligned(16)));
      *(i32x4*)tmp = v;
      int colbase = ((((r >> 3) ^ a) << 3) | (r & 7));
#pragma unroll
      for (int j = 0; j < 8; j++) sVt[a * 8 + j][colbase] = tmp[j];
    }
    // stage dist_emb window (fp32 -> bf16): sP[p] = dist[q0-r0+960 + p]
    const int dbase = q0 - r0 + 960;
    for (int ch = tid; ch < 1024; ch += 256) {
      int p = ch >> 3, c8 = (ch & 7) << 3;
      int g = dbase + p;
      if (g > 2046) g = 2046;  // pad row 127, never gathered
      const float* src = dist + (size_t)g * 64 + c8;
      pack8(&sP[p][c8], *(const f32x4*)src, *(const f32x4*)(src + 4));
    }
    __syncthreads();  // barrier A

    // --- QK^T ---
    f32x4 accS[4] = {};
#pragma unroll
    for (int t = 0; t < 4; t++) {
      int n = 16 * t + lb;
      bf16x8 b0 = ldb8(&sK[n][quad * 8]);
      bf16x8 b1 = ldb8(&sK[n][32 + quad * 8]);
      accS[t] = MFMA16(aq0, b0, accS[t]);
      accS[t] = MFMA16(aq1, b1, accS[t]);
    }
    // --- Gq, Gk (rel bias GEMMs), each wave its own 16-row strip ---
    bf16x8 ak0 = ldb8(&sK[row][quad * 8]);
    bf16x8 ak1 = ldb8(&sK[row][32 + quad * 8]);
#pragma unroll
    for (int u = 0; u < 8; u++) {
      int n = 16 * u + lb;
      bf16x8 p0 = ldb8(&sP[n][quad * 8]);
      bf16x8 p1 = ldb8(&sP[n][32 + quad * 8]);
      f32x4 gq = {}, gk = {};
      gq = MFMA16(aq0, p0, gq); gq = MFMA16(aq1, p1, gq);
      gk = MFMA16(ak0, p0, gk); gk = MFMA16(ak1, p1, gk);
#pragma unroll
      for (int i = 0; i < 4; i++) {
        sGq[16 * w + quad * 4 + i][16 * u + lb] = f2b(gq[i]);
        sGk[16 * w + quad * 4 + i][16 * u + lb] = f2b(gk[i]);
      }
    }
    __syncthreads();  // barrier B (sGk is read cross-wave)

    // --- bias gather + scale + online softmax ---
    float pr[4][4], rmax[4], rsum[4], alpha[4];
#pragma unroll
    for (int i = 0; i < 4; i++) rmax[i] = -3.0e38f;
#pragma unroll
    for (int t = 0; t < 4; t++) {
#pragma unroll
      for (int i = 0; i < 4; i++) {
        int rl = 16 * w + quad * 4 + i;  // local q row (own wave strip)
        int cl = 16 * t + lb;            // local k col
        int c = rl - cl + 63;            // delta window col, 0..126
        float s = (accS[t][i] + b2f(sGq[rl][c]) + b2f(sGk[cl][c])) * 0.125f;
        pr[t][i] = s;
        rmax[i] = fmaxf(rmax[i], s);
      }
    }
#pragma unroll
    for (int d = 1; d < 16; d <<= 1)
#pragma unroll
      for (int i = 0; i < 4; i++)
        rmax[i] = fmaxf(rmax[i], __shfl_xor(rmax[i], d, 64));
#pragma unroll
    for (int i = 0; i < 4; i++) {
      float mn = fmaxf(m_i[i], rmax[i]);
      alpha[i] = __expf(m_i[i] - mn);
      m_i[i] = mn;
      rsum[i] = 0.f;
    }
#pragma unroll
    for (int t = 0; t < 4; t++)
#pragma unroll
      for (int i = 0; i < 4; i++) {
        float e = __expf(pr[t][i] - m_i[i]);
        pr[t][i] = e;
        rsum[i] += e;
      }
#pragma unroll
    for (int d = 1; d < 16; d <<= 1)
#pragma unroll
      for (int i = 0; i < 4; i++)
        rsum[i] += __shfl_xor(rsum[i], d, 64);
#pragma unroll
    for (int i = 0; i < 4; i++) l_i[i] = l_i[i] * alpha[i] + rsum[i];

    // write probs (bf16) overlaying sGq cols [0,64) -- own-wave rows only;
    // all gather reads above already completed (wave-lockstep program order)
#pragma unroll
    for (int t = 0; t < 4; t++)
#pragma unroll
      for (int i = 0; i < 4; i++)
        sGq[16 * w + quad * 4 + i][16 * t + lb] = f2b(pr[t][i]);
    // rescale running context
#pragma unroll
    for (int t = 0; t < 4; t++)
#pragma unroll
      for (int i = 0; i < 4; i++) accO[t][i] *= alpha[i];

    // --- PV (A-operand: own-wave rows of the probs overlay; no barrier) ---
    bf16x8 ap0 = ldb8(&sGq[row][quad * 8]);
    bf16x8 ap1 = ldb8(&sGq[row][32 + quad * 8]);
#pragma unroll
    for (int t = 0; t < 4; t++) {
      int n = 16 * t + lb;
      int sw = (n >> 3) & 7;
      bf16x8 v0 = ldb8(&sVt[n][(quad ^ sw) << 3]);
      bf16x8 v1 = ldb8(&sVt[n][((4 + quad) ^ sw) << 3]);
      accO[t] = MFMA16(ap0, v0, accO[t]);
      accO[t] = MFMA16(ap1, v1, accO[t]);
    }
    __syncthreads();  // barrier C (protect sK/sVt/sP/sGk for next iter)
  }

  // epilogue: ctx = accO / l
  u16* Cb = ctx + (size_t)(b * S) * E + h * 64;
#pragma unroll
  for (int t = 0; t < 4; t++)
#pragma unroll
    for (int i = 0; i < 4; i++) {
      int rl = 16 * w + quad * 4 + i;
      Cb[(size_t)(q0 + rl) * E + 16 * t + lb] = f2b(accO[t][i] / l_i[i]);
    }
}

// ---------------------------------------------------------------------------
// Row LayerNorm: fp32 in [8192,1024], fp32 out.
// ---------------------------------------------------------------------------
__global__ __launch_bounds__(256) void lnorm(
    const float* __restrict__ Hp, const float* __restrict__ gamma,
    const float* __restrict__ beta, float* __restrict__ out) {
  __shared__ float red[8];
  const int rowb = blockIdx.x, tid = threadIdx.x;
  const float* hr = Hp + (size_t)rowb * 1024;
  f32x4 v = *(const f32x4*)&hr[tid * 4];
  float s = v.x + v.y + v.z + v.w;
  float q = v.x * v.x + v.y * v.y + v.z * v.z + v.w * v.w;
#pragma unroll
  for (int d = 1; d < 64; d <<= 1) {
    s += __shfl_xor(s, d, 64);
    q += __shfl_xor(q, d, 64);
  }
  int w = tid >> 6, lane = tid & 63;
  if (lane == 0) { red[w] = s; red[4 + w] = q; }
  __syncthreads();
  s = red[0] + red[1] + red[2] + red[3];
  q = red[4] + red[5] + red[6] + red[7];
  float mu = s * (1.f / 1024.f);
  float var = q * (1.f / 1024.f) - mu * mu;
  float rstd = rsqrtf(var + 1e-12f);
  float* orow = out + (size_t)rowb * 1024;
  f32x4 o;
#pragma unroll
  for (int j = 0; j < 4; j++) {
    int c = tid * 4 + j;
    o[j] = (v[j] - mu) * rstd * gamma[c] + beta[c];
  }
  *(f32x4*)&orow[tid * 4] = o;
}

// ---------------------------------------------------------------------------
extern "C" void kernel_launch(void* const* d_in, const int* in_sizes, int n_in,
                              void* d_out, int out_size, void* d_ws,
                              size_t ws_size, hipStream_t stream) {
  const float* X    = (const float*)d_in[0];
  const float* Wq   = (const float*)d_in[1];
  const float* bq   = (const float*)d_in[2];
  const float* Wk   = (const float*)d_in[3];
  const float* bk   = (const float*)d_in[4];
  const float* Wv   = (const float*)d_in[5];
  const float* bv   = (const float*)d_in[6];
  const float* dist = (const float*)d_in[7];
  const float* Wo   = (const float*)d_in[8];
  const float* bo   = (const float*)d_in[9];
  const float* gam  = (const float*)d_in[10];
  const float* bet  = (const float*)d_in[11];

  const size_t NE = (size_t)8192 * 1024;  // elements per [B*S, E] tensor
  char* ws = (char*)d_ws;
  u16* Qw = (u16*)(ws);                // bf16 [0, 2NE)
  u16* Kw = (u16*)(ws + 2 * NE);       // bf16 [2NE, 4NE)
  u16* Vw = (u16*)(ws + 4 * NE);       // bf16 [4NE, 6NE)
  u16* Cw = (u16*)(ws + 6 * NE);       // bf16 [6NE, 8NE)   (64 MB total)
  float* Hp = (float*)ws;              // fp32 pre-LN, overlays dead Q+K

  dim3 bb(256);
  dim3 gg(16, 64);
  gemm128<1, 0, 0><<<gg, bb, 0, stream>>>(X, Wq, bq, nullptr, nullptr, Qw, 8192, 1024, 1024);
  gemm128<1, 0, 0><<<gg, bb, 0, stream>>>(X, Wk, bk, nullptr, nullptr, Kw, 8192, 1024, 1024);
  gemm128<1, 0, 0><<<gg, bb, 0, stream>>>(X, Wv, bv, nullptr, nullptr, Vw, 8192, 1024, 1024);
  attn<<<dim3(16, 128), bb, 0, stream>>>(Qw, Kw, Vw, dist, Cw);
  gemm128<0, 1, 1><<<gg, bb, 0, stream>>>(Cw, Wo, bo, X, Hp, nullptr, 8192, 1024, 1024);
  lnorm<<<dim3(8192), bb, 0, stream>>>(Hp, gam, bet, (float*)d_out);
}

// Round 4
// 677.130 us; speedup vs baseline: 1.5584x; 1.1126x over previous
//
#include <hip/hip_runtime.h>

// ---------------------------------------------------------------------------
// BertAttention (relative_key_query) on MI355X. FP32 I/O, bf16 MFMA compute.
// B=8 S=1024 E=1024 H=16 D=64 M=1024
// R4: packed bf16 cvt, transposed G store (b64), DPP reductions, circular
// dist-window, paired V-transpose, probs->sK overlay, 128x128 GEMM tiles.
// ---------------------------------------------------------------------------

typedef unsigned short u16;
typedef unsigned int u32;
typedef unsigned long long u64;
typedef __bf16 bf16x8 __attribute__((ext_vector_type(8)));
typedef float  f32x4  __attribute__((ext_vector_type(4)));
typedef int    i32x4  __attribute__((ext_vector_type(4)));

__device__ __forceinline__ float b2f(u16 u) {
  union { u32 i; float f; } x;
  x.i = ((u32)u) << 16;
  return x.f;
}
__device__ __forceinline__ u16 f2b_manual(float f) {
  union { float f; u32 u; } x;
  x.f = f;
  return (u16)((x.u + 0x7FFFu + ((x.u >> 16) & 1u)) >> 16);
}
#if __has_builtin(__builtin_amdgcn_cvt_pk_bf16_f32)
typedef __bf16 bf16x2 __attribute__((ext_vector_type(2)));
__device__ __forceinline__ u32 cvt2(float a, float b) {
  union { bf16x2 v; u32 u; } x;
  x.v = __builtin_amdgcn_cvt_pk_bf16_f32(a, b);
  return x.u;
}
#else
__device__ __forceinline__ u32 cvt2(float a, float b) {
  return (u32)f2b_manual(a) | ((u32)f2b_manual(b) << 16);
}
#endif
__device__ __forceinline__ u16 f2b(float f) { return (u16)(cvt2(f, f) & 0xffffu); }

union LdU { i32x4 i4; bf16x8 b8; };
__device__ __forceinline__ bf16x8 ldb8(const u16* p) {
  LdU u; u.i4 = *(const i32x4*)p; return u.b8;
}
// fp32x8 -> bf16x8 staged write
__device__ __forceinline__ void pack8(u16* dst, const float* src) {
  f32x4 lo = *(const f32x4*)src, hi = *(const f32x4*)(src + 4);
  i32x4 v;
  v.x = (int)cvt2(lo.x, lo.y); v.y = (int)cvt2(lo.z, lo.w);
  v.z = (int)cvt2(hi.x, hi.y); v.w = (int)cvt2(hi.z, hi.w);
  *(i32x4*)dst = v;
}
#define MFMA16(a, b, c) __builtin_amdgcn_mfma_f32_16x16x32_bf16((a), (b), (c), 0, 0, 0)

// DPP 16-lane butterfly reduction (masks 1,2,7,15 span the 4 row bits)
template <int C>
__device__ __forceinline__ float dppmov(float x) {
  union { float f; int i; } a, r;
  a.f = x;
  r.i = __builtin_amdgcn_update_dpp(0, a.i, C, 0xF, 0xF, true);
  return r.f;
}
__device__ __forceinline__ float rmax16(float x) {
  x = fmaxf(x, dppmov<0xB1>(x));   // quad_perm xor1
  x = fmaxf(x, dppmov<0x4E>(x));   // quad_perm xor2
  x = fmaxf(x, dppmov<0x141>(x));  // row_half_mirror (^7)
  x = fmaxf(x, dppmov<0x140>(x));  // row_mirror (^15)
  return x;
}
__device__ __forceinline__ float rsum16(float x) {
  x += dppmov<0xB1>(x);
  x += dppmov<0x4E>(x);
  x += dppmov<0x141>(x);
  x += dppmov<0x140>(x);
  return x;
}
__device__ __forceinline__ float fexp2(float x) {
#if __has_builtin(__builtin_amdgcn_exp2f)
  return __builtin_amdgcn_exp2f(x);
#else
  return exp2f(x);
#endif
}

// ---------------------------------------------------------------------------
// GEMM: out[N,M] = A[N,K] @ W[K,M] + bias (+ residual). 128x128 block tile,
// BK=64, 4 waves, each wave a 32x128 strip. W staged transposed with paired-k
// b32 writes + XOR column-group swizzle.
// ---------------------------------------------------------------------------
template <int AF32, int RESID, int OUTF32>
__global__ __launch_bounds__(256, 3) void gemm128(
    const void* __restrict__ Ap, const float* __restrict__ W,
    const float* __restrict__ bias, const float* __restrict__ resid,
    float* __restrict__ outF, u16* __restrict__ outB, int N, int K, int M) {
  __shared__ u16 sA[128][72];  // rows x k, +8 pad
  __shared__ u16 sW[128][72];  // Wt[n][k'], col-group swizzled

  const int tid = threadIdx.x;
  const int lane = tid & 63, w = tid >> 6;
  const int quad = lane >> 4, lb = lane & 15;
  const int m0 = blockIdx.x * 128, n0 = blockIdx.y * 128;

  f32x4 acc[2][8] = {};

  for (int k0 = 0; k0 < K; k0 += 64) {
    // stage A tile (128x64)
#pragma unroll
    for (int ch = tid; ch < 1024; ch += 256) {
      int r = ch >> 3, c8 = (ch & 7) << 3;
      if (AF32) {
        pack8(&sA[r][c8], (const float*)Ap + (size_t)(n0 + r) * K + k0 + c8);
      } else {
        const u16* src = (const u16*)Ap + (size_t)(n0 + r) * K + k0 + c8;
        *(i32x4*)&sA[r][c8] = *(const i32x4*)src;
      }
    }
    // stage W transposed (64k x 128m), paired along k -> b32 writes
#pragma unroll
    for (int it = 0; it < 2; it++) {
      int kp = (tid >> 4) + (it << 4);  // 0..31 k-pair
      int ag = tid & 15;                // n-group (8 cols)
      const float* src = W + (size_t)(k0 + 2 * kp) * M + m0 + ag * 8;
      f32x4 xa0 = *(const f32x4*)src, xa1 = *(const f32x4*)(src + 4);
      f32x4 xb0 = *(const f32x4*)(src + M), xb1 = *(const f32x4*)(src + M + 4);
      int colb = (((kp >> 2) ^ (ag & 7)) << 3) | ((2 * kp) & 7);
#pragma unroll
      for (int j = 0; j < 8; j++) {
        float lo = j < 4 ? xa0[j] : xa1[j - 4];
        float hi = j < 4 ? xb0[j] : xb1[j - 4];
        *(u32*)&sW[ag * 8 + j][colb] = cvt2(lo, hi);
      }
    }
    __syncthreads();

    const int r0 = 32 * w + lb;
    bf16x8 a00 = ldb8(&sA[r0][quad * 8]);
    bf16x8 a01 = ldb8(&sA[r0][32 + quad * 8]);
    bf16x8 a10 = ldb8(&sA[r0 + 16][quad * 8]);
    bf16x8 a11 = ldb8(&sA[r0 + 16][32 + quad * 8]);
#pragma unroll
    for (int t = 0; t < 8; t++) {
      int n = 16 * t + lb;
      int sw = (n >> 3) & 7;
      bf16x8 b0 = ldb8(&sW[n][(quad ^ sw) << 3]);
      bf16x8 b1 = ldb8(&sW[n][((4 + quad) ^ sw) << 3]);
      acc[0][t] = MFMA16(a00, b0, acc[0][t]);
      acc[0][t] = MFMA16(a01, b1, acc[0][t]);
      acc[1][t] = MFMA16(a10, b0, acc[1][t]);
      acc[1][t] = MFMA16(a11, b1, acc[1][t]);
    }
    __syncthreads();
  }

#pragma unroll
  for (int half = 0; half < 2; half++)
#pragma unroll
    for (int t = 0; t < 8; t++) {
      int col = m0 + 16 * t + lb;
      float bv = bias[col];
#pragma unroll
      for (int i = 0; i < 4; i++) {
        int rowg = n0 + 32 * w + 16 * half + quad * 4 + i;
        float v = acc[half][t][i] + bv;
        if (RESID) v += resid[(size_t)rowg * M + col];
        if (OUTF32) outF[(size_t)rowg * M + col] = v;
        else        outB[(size_t)rowg * M + col] = f2b(v);
      }
    }
}

// ---------------------------------------------------------------------------
// Fused attention: one block = (b, h, 64 q-rows). Online softmax over 16
// k-tiles of 64. Rel bias: Gq = Qt @ Pwin^T, Gk = Kt @ Pwin^T via MFMA, G
// stored TRANSPOSED (GqT[p][rl]) with b64 writes; gather
// Gq[rl][rl-cl+63] + Gk[cl][rl-cl+63] as u16 reads. dist window is a
// circular buffer (shifts 64/ktile). Probs overlay sK (dead after barrier B).
// ---------------------------------------------------------------------------
__global__ __launch_bounds__(256) void attn(
    const u16* __restrict__ Q, const u16* __restrict__ Kv,
    const u16* __restrict__ V, const float* __restrict__ dist,
    u16* __restrict__ ctx) {
  __shared__ u16 sQ[64][72];
  __shared__ u16 sK[64][72];      // probs overlay after barrier B
  __shared__ u16 sVt[64][72];     // V^T [d][r'], swizzled
  __shared__ u16 sP[128][72];     // dist window, circular (phys = log ^ par*64)
  __shared__ u16 sGqT[128][68];   // GqT[p][rl]
  __shared__ u16 sGkT[128][68];   // GkT[p][cl]

  const int tid = threadIdx.x;
  const int lane = tid & 63, w = tid >> 6;
  const int quad = lane >> 4, lb = lane & 15;
  const int bh = blockIdx.y, b = bh >> 4, h = bh & 15;
  const int q0 = blockIdx.x << 6;
  const int S = 1024, E = 1024;
  const u16* Qb = Q  + (size_t)(b * S) * E + h * 64;
  const u16* Kb = Kv + (size_t)(b * S) * E + h * 64;
  const u16* Vb = V  + (size_t)(b * S) * E + h * 64;

  // stage Q tile once
  for (int ch = tid; ch < 512; ch += 256) {
    int r = ch >> 3, c8 = (ch & 7) << 3;
    *(i32x4*)&sQ[r][c8] = *(const i32x4*)&Qb[(size_t)(q0 + r) * E + c8];
  }
  __syncthreads();

  const int row = 16 * w + lb;
  bf16x8 aq0 = ldb8(&sQ[row][quad * 8]);
  bf16x8 aq1 = ldb8(&sQ[row][32 + quad * 8]);

  f32x4 accO[4] = {};
  float m_i[4], l_i[4];
#pragma unroll
  for (int i = 0; i < 4; i++) { m_i[i] = -1.0e30f; l_i[i] = 0.f; }
  const float C2 = 0.125f * 1.44269504f;  // score scale folded w/ log2(e)

  for (int kt = 0; kt < 16; kt++) {
    const int r0 = kt << 6;
    const int xorv = (kt & 1) << 6;
    // stage K tile
    for (int ch = tid; ch < 512; ch += 256) {
      int r = ch >> 3, c8 = (ch & 7) << 3;
      *(i32x4*)&sK[r][c8] = *(const i32x4*)&Kb[(size_t)(r0 + r) * E + c8];
    }
    // stage V transposed: thread -> (row-pair rp, d-group a); b32 pair writes
    {
      int rp = tid >> 3, a = tid & 7;
      const u16* src = &Vb[(size_t)(r0 + 2 * rp) * E + a * 8];
      i32x4 va = *(const i32x4*)src;
      i32x4 vb2 = *(const i32x4*)(src + E);
      u16 ta[8] __attribute__((aligned(16)));
      u16 tb[8] __attribute__((aligned(16)));
      *(i32x4*)ta = va; *(i32x4*)tb = vb2;
      int colb = ((((rp >> 2) ^ a) << 3) | ((2 * rp) & 7));
#pragma unroll
      for (int j = 0; j < 8; j++) {
        u32 pair = (u32)ta[j] | ((u32)tb[j] << 16);
        *(u32*)&sVt[a * 8 + j][colb] = pair;
      }
    }
    // stage dist window (circular): kt=0 -> all 128 rows, else 64 new rows
    const int dbase = q0 - r0 + 960;
    if (kt == 0) {
      for (int ch = tid; ch < 1024; ch += 256) {
        int p = ch >> 3, c8 = (ch & 7) << 3;
        int g = dbase + p;
        if (g > 2046) g = 2046;  // pad row (col 127, never gathered)
        pack8(&sP[p][c8], dist + (size_t)g * 64 + c8);
      }
    } else {
      for (int ch = tid; ch < 512; ch += 256) {
        int p = ch >> 3, c8 = (ch & 7) << 3;   // new logical rows [0,64)
        int g = dbase + p;                      // in-range by construction
        pack8(&sP[p ^ xorv][c8], dist + (size_t)g * 64 + c8);
      }
    }
    __syncthreads();  // barrier A

    // --- QK^T ---
    f32x4 accS[4] = {};
#pragma unroll
    for (int t = 0; t < 4; t++) {
      int n = 16 * t + lb;
      bf16x8 b0 = ldb8(&sK[n][quad * 8]);
      bf16x8 b1 = ldb8(&sK[n][32 + quad * 8]);
      accS[t] = MFMA16(aq0, b0, accS[t]);
      accS[t] = MFMA16(aq1, b1, accS[t]);
    }
    // --- Gq, Gk rel-bias GEMMs; store transposed via b64 ---
    bf16x8 ak0 = ldb8(&sK[row][quad * 8]);
    bf16x8 ak1 = ldb8(&sK[row][32 + quad * 8]);
#pragma unroll
    for (int u = 0; u < 8; u++) {
      int np = (16 * u + lb) ^ xorv;  // physical sP row for logical col
      bf16x8 p0 = ldb8(&sP[np][quad * 8]);
      bf16x8 p1 = ldb8(&sP[np][32 + quad * 8]);
      f32x4 gq = {}, gk = {};
      gq = MFMA16(aq0, p0, gq); gq = MFMA16(aq1, p1, gq);
      gk = MFMA16(ak0, p0, gk); gk = MFMA16(ak1, p1, gk);
      u64 qv = (u64)cvt2(gq[0], gq[1]) | ((u64)cvt2(gq[2], gq[3]) << 32);
      u64 kv = (u64)cvt2(gk[0], gk[1]) | ((u64)cvt2(gk[2], gk[3]) << 32);
      *(u64*)&sGqT[16 * u + lb][16 * w + 4 * quad] = qv;
      *(u64*)&sGkT[16 * u + lb][16 * w + 4 * quad] = kv;
    }
    __syncthreads();  // barrier B (G read cross-wave; sK dead after this)

    // --- bias gather + scaled-log2 online softmax ---
    float pr[4][4], rmax[4], rsum[4], alpha[4];
#pragma unroll
    for (int i = 0; i < 4; i++) rmax[i] = -1.0e30f;
#pragma unroll
    for (int t = 0; t < 4; t++) {
#pragma unroll
      for (int i = 0; i < 4; i++) {
        int rl = 16 * w + quad * 4 + i;  // local q row
        int cl = 16 * t + lb;            // local k col
        int c = rl - cl + 63;            // window col 0..126
        float s = (accS[t][i] + b2f(sGqT[c][rl]) + b2f(sGkT[c][cl])) * C2;
        pr[t][i] = s;
        rmax[i] = fmaxf(rmax[i], s);
      }
    }
#pragma unroll
    for (int i = 0; i < 4; i++) rmax[i] = rmax16(rmax[i]);
#pragma unroll
    for (int i = 0; i < 4; i++) {
      float mn = fmaxf(m_i[i], rmax[i]);
      alpha[i] = fexp2(m_i[i] - mn);
      m_i[i] = mn;
      rsum[i] = 0.f;
    }
#pragma unroll
    for (int t = 0; t < 4; t++)
#pragma unroll
      for (int i = 0; i < 4; i++) {
        float e = fexp2(pr[t][i] - m_i[i]);
        pr[t][i] = e;
        rsum[i] += e;
      }
#pragma unroll
    for (int i = 0; i < 4; i++) {
      rsum[i] = rsum16(rsum[i]);
      l_i[i] = l_i[i] * alpha[i] + rsum[i];
    }

    // probs -> sK overlay (own-wave rows only; sK dead until restaged)
#pragma unroll
    for (int t = 0; t < 4; t++)
#pragma unroll
      for (int i = 0; i < 4; i++)
        sK[16 * w + quad * 4 + i][16 * t + lb] = f2b(pr[t][i]);
#pragma unroll
    for (int t = 0; t < 4; t++)
#pragma unroll
      for (int i = 0; i < 4; i++) accO[t][i] *= alpha[i];

    // --- PV (A: own-wave probs rows; no barrier needed) ---
    bf16x8 ap0 = ldb8(&sK[row][quad * 8]);
    bf16x8 ap1 = ldb8(&sK[row][32 + quad * 8]);
#pragma unroll
    for (int t = 0; t < 4; t++) {
      int n = 16 * t + lb;
      int sw = (n >> 3) & 7;
      bf16x8 v0 = ldb8(&sVt[n][(quad ^ sw) << 3]);
      bf16x8 v1 = ldb8(&sVt[n][((4 + quad) ^ sw) << 3]);
      accO[t] = MFMA16(ap0, v0, accO[t]);
      accO[t] = MFMA16(ap1, v1, accO[t]);
    }
    __syncthreads();  // barrier C (protect sK/sVt/sP for next iter)
  }

  // epilogue: ctx = accO / l
  u16* Cb = ctx + (size_t)(b * S) * E + h * 64;
#pragma unroll
  for (int t = 0; t < 4; t++)
#pragma unroll
    for (int i = 0; i < 4; i++) {
      int rl = 16 * w + quad * 4 + i;
      Cb[(size_t)(q0 + rl) * E + 16 * t + lb] = f2b(accO[t][i] / l_i[i]);
    }
}

// ---------------------------------------------------------------------------
// Row LayerNorm: fp32 in [8192,1024], fp32 out.
// ---------------------------------------------------------------------------
__global__ __launch_bounds__(256) void lnorm(
    const float* __restrict__ Hp, const float* __restrict__ gamma,
    const float* __restrict__ beta, float* __restrict__ out) {
  __shared__ float red[8];
  const int rowb = blockIdx.x, tid = threadIdx.x;
  const float* hr = Hp + (size_t)rowb * 1024;
  f32x4 v = *(const f32x4*)&hr[tid * 4];
  float s = v.x + v.y + v.z + v.w;
  float q = v.x * v.x + v.y * v.y + v.z * v.z + v.w * v.w;
#pragma unroll
  for (int d = 1; d < 64; d <<= 1) {
    s += __shfl_xor(s, d, 64);
    q += __shfl_xor(q, d, 64);
  }
  int w = tid >> 6, lane = tid & 63;
  if (lane == 0) { red[w] = s; red[4 + w] = q; }
  __syncthreads();
  s = red[0] + red[1] + red[2] + red[3];
  q = red[4] + red[5] + red[6] + red[7];
  float mu = s * (1.f / 1024.f);
  float var = q * (1.f / 1024.f) - mu * mu;
  float rstd = rsqrtf(var + 1e-12f);
  float* orow = out + (size_t)rowb * 1024;
  f32x4 o;
#pragma unroll
  for (int j = 0; j < 4; j++) {
    int c = tid * 4 + j;
    o[j] = (v[j] - mu) * rstd * gamma[c] + beta[c];
  }
  *(f32x4*)&orow[tid * 4] = o;
}

// ---------------------------------------------------------------------------
extern "C" void kernel_launch(void* const* d_in, const int* in_sizes, int n_in,
                              void* d_out, int out_size, void* d_ws,
                              size_t ws_size, hipStream_t stream) {
  const float* X    = (const float*)d_in[0];
  const float* Wq   = (const float*)d_in[1];
  const float* bq   = (const float*)d_in[2];
  const float* Wk   = (const float*)d_in[3];
  const float* bk   = (const float*)d_in[4];
  const float* Wv   = (const float*)d_in[5];
  const float* bv   = (const float*)d_in[6];
  const float* dist = (const float*)d_in[7];
  const float* Wo   = (const float*)d_in[8];
  const float* bo   = (const float*)d_in[9];
  const float* gam  = (const float*)d_in[10];
  const float* bet  = (const float*)d_in[11];

  const size_t NE = (size_t)8192 * 1024;
  char* ws = (char*)d_ws;
  u16* Qw = (u16*)(ws);
  u16* Kw = (u16*)(ws + 2 * NE);
  u16* Vw = (u16*)(ws + 4 * NE);
  u16* Cw = (u16*)(ws + 6 * NE);
  float* Hp = (float*)ws;  // fp32 pre-LN, overlays dead Q+K

  dim3 bb(256);
  dim3 gg(8, 64);
  gemm128<1, 0, 0><<<gg, bb, 0, stream>>>(X, Wq, bq, nullptr, nullptr, Qw, 8192, 1024, 1024);
  gemm128<1, 0, 0><<<gg, bb, 0, stream>>>(X, Wk, bk, nullptr, nullptr, Kw, 8192, 1024, 1024);
  gemm128<1, 0, 0><<<gg, bb, 0, stream>>>(X, Wv, bv, nullptr, nullptr, Vw, 8192, 1024, 1024);
  attn<<<dim3(16, 128), bb, 0, stream>>>(Qw, Kw, Vw, dist, Cw);
  gemm128<0, 1, 1><<<gg, bb, 0, stream>>>(Cw, Wo, bo, X, Hp, nullptr, 8192, 1024, 1024);
  lnorm<<<dim3(8192), bb, 0, stream>>>(Hp, gam, bet, (float*)d_out);
}

// Round 5
// 572.853 us; speedup vs baseline: 1.8420x; 1.1820x over previous
//
#include <hip/hip_runtime.h>

// ---------------------------------------------------------------------------
// BertAttention (relative_key_query) on MI355X. FP32 I/O, bf16 MFMA compute.
// B=8 S=1024 E=1024 H=16 D=64 M=1024
// R5: pre-convert X->bf16 and W->bf16^T into d_out scratch (pure-bf16 GEMMs,
// zero-VALU staging); attn: fixed-max softmax (no online rescale), sGqT
// stride 66 (odd word stride -> conflict-free gather).
// ---------------------------------------------------------------------------

typedef unsigned short u16;
typedef unsigned int u32;
typedef unsigned long long u64;
typedef __bf16 bf16x8 __attribute__((ext_vector_type(8)));
typedef float  f32x4  __attribute__((ext_vector_type(4)));
typedef int    i32x4  __attribute__((ext_vector_type(4)));

__device__ __forceinline__ float b2f(u16 u) {
  union { u32 i; float f; } x;
  x.i = ((u32)u) << 16;
  return x.f;
}
__device__ __forceinline__ u16 f2b_manual(float f) {
  union { float f; u32 u; } x;
  x.f = f;
  return (u16)((x.u + 0x7FFFu + ((x.u >> 16) & 1u)) >> 16);
}
#if __has_builtin(__builtin_amdgcn_cvt_pk_bf16_f32)
typedef __bf16 bf16x2 __attribute__((ext_vector_type(2)));
__device__ __forceinline__ u32 cvt2(float a, float b) {
  union { bf16x2 v; u32 u; } x;
  x.v = __builtin_amdgcn_cvt_pk_bf16_f32(a, b);
  return x.u;
}
#else
__device__ __forceinline__ u32 cvt2(float a, float b) {
  return (u32)f2b_manual(a) | ((u32)f2b_manual(b) << 16);
}
#endif
__device__ __forceinline__ u16 f2b(float f) { return (u16)(cvt2(f, f) & 0xffffu); }

union LdU { i32x4 i4; bf16x8 b8; };
__device__ __forceinline__ bf16x8 ldb8(const u16* p) {
  LdU u; u.i4 = *(const i32x4*)p; return u.b8;
}
__device__ __forceinline__ void pack8(u16* dst, const float* src) {
  f32x4 lo = *(const f32x4*)src, hi = *(const f32x4*)(src + 4);
  i32x4 v;
  v.x = (int)cvt2(lo.x, lo.y); v.y = (int)cvt2(lo.z, lo.w);
  v.z = (int)cvt2(hi.x, hi.y); v.w = (int)cvt2(hi.z, hi.w);
  *(i32x4*)dst = v;
}
#define MFMA16(a, b, c) __builtin_amdgcn_mfma_f32_16x16x32_bf16((a), (b), (c), 0, 0, 0)

// DPP 16-lane butterfly sum (masks 1,2,7,15 span the 4 row bits)
template <int C>
__device__ __forceinline__ float dppmov(float x) {
  union { float f; int i; } a, r;
  a.f = x;
  r.i = __builtin_amdgcn_update_dpp(0, a.i, C, 0xF, 0xF, true);
  return r.f;
}
__device__ __forceinline__ float rsum16(float x) {
  x += dppmov<0xB1>(x);   // quad_perm xor1
  x += dppmov<0x4E>(x);   // quad_perm xor2
  x += dppmov<0x141>(x);  // row_half_mirror (^7)
  x += dppmov<0x140>(x);  // row_mirror (^15)
  return x;
}
__device__ __forceinline__ float fexp2(float x) {
#if __has_builtin(__builtin_amdgcn_exp2f)
  return __builtin_amdgcn_exp2f(x);
#else
  return exp2f(x);
#endif
}

// ---------------------------------------------------------------------------
// convX: fp32 -> bf16 straight cast, 8 elems/thread.
// ---------------------------------------------------------------------------
__global__ __launch_bounds__(256) void convX(
    const float* __restrict__ X, u16* __restrict__ Xb) {
  int i = (blockIdx.x * 256 + threadIdx.x) * 8;
  pack8(&Xb[i], &X[i]);
}

// ---------------------------------------------------------------------------
// convWt: W[1024][1024] fp32 -> Wt[m][k] bf16 (transposed), 64x64 LDS tiles.
// ---------------------------------------------------------------------------
__global__ __launch_bounds__(256) void convWt(
    const float* __restrict__ W, u16* __restrict__ Wt) {
  __shared__ float tile[64][65];
  const int tid = threadIdx.x;
  const int k0 = blockIdx.x * 64, m0 = blockIdx.y * 64;
#pragma unroll
  for (int it = 0; it < 4; it++) {
    int row = (tid >> 4) + 16 * it;   // k-local
    int col = (tid & 15) * 4;         // m-local
    f32x4 v = *(const f32x4*)&W[(size_t)(k0 + row) * 1024 + m0 + col];
    tile[row][col] = v.x; tile[row][col + 1] = v.y;
    tile[row][col + 2] = v.z; tile[row][col + 3] = v.w;
  }
  __syncthreads();
#pragma unroll
  for (int it = 0; it < 4; it++) {
    int mr = (tid >> 4) + 16 * it;    // m-local
    int kc = (tid & 15) * 4;          // k-local
    u32 w0 = cvt2(tile[kc][mr], tile[kc + 1][mr]);
    u32 w1 = cvt2(tile[kc + 2][mr], tile[kc + 3][mr]);
    *(u64*)&Wt[(size_t)(m0 + mr) * 1024 + k0 + kc] = (u64)w0 | ((u64)w1 << 32);
  }
}

// ---------------------------------------------------------------------------
// GEMM: out[N,M] = A[N,K] @ W[K,M] + bias (+ residual). Both operands bf16
// (Wt pre-transposed [m][k]) -> direct-copy staging, no cvt/transpose.
// 128x64 tile, 4 waves x 32x64 strips (R3-proven shape).
// ---------------------------------------------------------------------------
template <int RESID, int OUTF32>
__global__ __launch_bounds__(256) void gemm_bb(
    const u16* __restrict__ A, const u16* __restrict__ Wt,
    const float* __restrict__ bias, const float* __restrict__ resid,
    float* __restrict__ outF, u16* __restrict__ outB, int N, int K, int M) {
  __shared__ u16 sA[128][72];
  __shared__ u16 sW[64][72];  // sW[n][k] = Wt[m0+n][k0+k]

  const int tid = threadIdx.x;
  const int lane = tid & 63, w = tid >> 6;
  const int quad = lane >> 4, lb = lane & 15;
  const int m0 = blockIdx.x * 64, n0 = blockIdx.y * 128;

  f32x4 acc[2][4] = {};

  for (int k0 = 0; k0 < K; k0 += 64) {
#pragma unroll
    for (int ch = tid; ch < 1024; ch += 256) {
      int r = ch >> 3, c8 = (ch & 7) << 3;
      *(i32x4*)&sA[r][c8] = *(const i32x4*)&A[(size_t)(n0 + r) * K + k0 + c8];
    }
#pragma unroll
    for (int ch = tid; ch < 512; ch += 256) {
      int n = ch >> 3, c8 = (ch & 7) << 3;
      *(i32x4*)&sW[n][c8] = *(const i32x4*)&Wt[(size_t)(m0 + n) * K + k0 + c8];
    }
    __syncthreads();

    const int r0 = 32 * w + lb;
    bf16x8 a00 = ldb8(&sA[r0][quad * 8]);
    bf16x8 a01 = ldb8(&sA[r0][32 + quad * 8]);
    bf16x8 a10 = ldb8(&sA[r0 + 16][quad * 8]);
    bf16x8 a11 = ldb8(&sA[r0 + 16][32 + quad * 8]);
#pragma unroll
    for (int t = 0; t < 4; t++) {
      int n = 16 * t + lb;
      bf16x8 b0 = ldb8(&sW[n][quad * 8]);
      bf16x8 b1 = ldb8(&sW[n][32 + quad * 8]);
      acc[0][t] = MFMA16(a00, b0, acc[0][t]);
      acc[0][t] = MFMA16(a01, b1, acc[0][t]);
      acc[1][t] = MFMA16(a10, b0, acc[1][t]);
      acc[1][t] = MFMA16(a11, b1, acc[1][t]);
    }
    __syncthreads();
  }

#pragma unroll
  for (int half = 0; half < 2; half++)
#pragma unroll
    for (int t = 0; t < 4; t++) {
      int col = m0 + 16 * t + lb;
      float bv = bias[col];
#pragma unroll
      for (int i = 0; i < 4; i++) {
        int rowg = n0 + 32 * w + 16 * half + quad * 4 + i;
        float v = acc[half][t][i] + bv;
        if (RESID) v += resid[(size_t)rowg * M + col];
        if (OUTF32) outF[(size_t)rowg * M + col] = v;
        else        outB[(size_t)rowg * M + col] = f2b(v);
      }
    }
}

// ---------------------------------------------------------------------------
// Fused attention: one block = (b, h, 64 q-rows), 16 k-tiles of 64.
// Rel bias: Gq = Qt @ Pwin^T, Gk = Kt @ Pwin^T via MFMA, stored transposed;
// gather Gq[rl][rl-cl+63] + Gk[cl][rl-cl+63]. Fixed-max softmax (scores
// bounded; exp2 domain) -> no online max/rescale. sGqT stride 66 (odd word
// stride: conflict-free gather); sGkT stride 68 (already stride-distributed).
// ---------------------------------------------------------------------------
__global__ __launch_bounds__(256) void attn(
    const u16* __restrict__ Q, const u16* __restrict__ Kv,
    const u16* __restrict__ V, const float* __restrict__ dist,
    u16* __restrict__ ctx) {
  __shared__ u16 sQ[64][72];
  __shared__ u16 sK[64][72];      // probs overlay after barrier B
  __shared__ u16 sVt[64][72];     // V^T [d][r'], swizzled
  __shared__ u16 sP[128][72];     // dist window, circular (phys = log ^ par*64)
  __shared__ u16 sGqT[128][66];   // GqT[p][rl], odd word stride
  __shared__ u16 sGkT[128][68];   // GkT[p][cl]

  const int tid = threadIdx.x;
  const int lane = tid & 63, w = tid >> 6;
  const int quad = lane >> 4, lb = lane & 15;
  const int bh = blockIdx.y, b = bh >> 4, h = bh & 15;
  const int q0 = blockIdx.x << 6;
  const int S = 1024, E = 1024;
  const u16* Qb = Q  + (size_t)(b * S) * E + h * 64;
  const u16* Kb = Kv + (size_t)(b * S) * E + h * 64;
  const u16* Vb = V  + (size_t)(b * S) * E + h * 64;

  for (int ch = tid; ch < 512; ch += 256) {
    int r = ch >> 3, c8 = (ch & 7) << 3;
    *(i32x4*)&sQ[r][c8] = *(const i32x4*)&Qb[(size_t)(q0 + r) * E + c8];
  }
  __syncthreads();

  const int row = 16 * w + lb;
  bf16x8 aq0 = ldb8(&sQ[row][quad * 8]);
  bf16x8 aq1 = ldb8(&sQ[row][32 + quad * 8]);

  f32x4 accO[4] = {};
  float l_i[4] = {0.f, 0.f, 0.f, 0.f};
  const float C2 = 0.125f * 1.44269504f;  // score scale folded w/ log2(e)

  for (int kt = 0; kt < 16; kt++) {
    const int r0 = kt << 6;
    const int xorv = (kt & 1) << 6;
    // stage K tile
    for (int ch = tid; ch < 512; ch += 256) {
      int r = ch >> 3, c8 = (ch & 7) << 3;
      *(i32x4*)&sK[r][c8] = *(const i32x4*)&Kb[(size_t)(r0 + r) * E + c8];
    }
    // stage V transposed (paired b32 writes, XOR swizzle)
    {
      int rp = tid >> 3, a = tid & 7;
      const u16* src = &Vb[(size_t)(r0 + 2 * rp) * E + a * 8];
      i32x4 va = *(const i32x4*)src;
      i32x4 vb2 = *(const i32x4*)(src + E);
      u16 ta[8] __attribute__((aligned(16)));
      u16 tb[8] __attribute__((aligned(16)));
      *(i32x4*)ta = va; *(i32x4*)tb = vb2;
      int colb = ((((rp >> 2) ^ a) << 3) | ((2 * rp) & 7));
#pragma unroll
      for (int j = 0; j < 8; j++) {
        u32 pair = (u32)ta[j] | ((u32)tb[j] << 16);
        *(u32*)&sVt[a * 8 + j][colb] = pair;
      }
    }
    // stage dist window (circular): kt=0 all 128 rows, else 64 new rows
    const int dbase = q0 - r0 + 960;
    if (kt == 0) {
      for (int ch = tid; ch < 1024; ch += 256) {
        int p = ch >> 3, c8 = (ch & 7) << 3;
        int g = dbase + p;
        if (g > 2046) g = 2046;
        pack8(&sP[p][c8], dist + (size_t)g * 64 + c8);
      }
    } else {
      for (int ch = tid; ch < 512; ch += 256) {
        int p = ch >> 3, c8 = (ch & 7) << 3;
        int g = dbase + p;
        pack8(&sP[p ^ xorv][c8], dist + (size_t)g * 64 + c8);
      }
    }
    __syncthreads();  // barrier A

    // --- QK^T ---
    f32x4 accS[4] = {};
#pragma unroll
    for (int t = 0; t < 4; t++) {
      int n = 16 * t + lb;
      bf16x8 b0 = ldb8(&sK[n][quad * 8]);
      bf16x8 b1 = ldb8(&sK[n][32 + quad * 8]);
      accS[t] = MFMA16(aq0, b0, accS[t]);
      accS[t] = MFMA16(aq1, b1, accS[t]);
    }
    // --- Gq, Gk rel-bias GEMMs; store transposed ---
    bf16x8 ak0 = ldb8(&sK[row][quad * 8]);
    bf16x8 ak1 = ldb8(&sK[row][32 + quad * 8]);
#pragma unroll
    for (int u = 0; u < 8; u++) {
      int np = (16 * u + lb) ^ xorv;
      bf16x8 p0 = ldb8(&sP[np][quad * 8]);
      bf16x8 p1 = ldb8(&sP[np][32 + quad * 8]);
      f32x4 gq = {}, gk = {};
      gq = MFMA16(aq0, p0, gq); gq = MFMA16(aq1, p1, gq);
      gk = MFMA16(ak0, p0, gk); gk = MFMA16(ak1, p1, gk);
      // sGqT: 2x b32 (base 4B-aligned; odd row stride)
      *(u32*)&sGqT[16 * u + lb][16 * w + 4 * quad] = cvt2(gq[0], gq[1]);
      *(u32*)&sGqT[16 * u + lb][16 * w + 4 * quad + 2] = cvt2(gq[2], gq[3]);
      u64 kv = (u64)cvt2(gk[0], gk[1]) | ((u64)cvt2(gk[2], gk[3]) << 32);
      *(u64*)&sGkT[16 * u + lb][16 * w + 4 * quad] = kv;
    }
    __syncthreads();  // barrier B (G read cross-wave; sK dead after this)

    // --- bias gather + fixed-max softmax (exp2 domain) ---
    float pr[4][4], rsum[4] = {0.f, 0.f, 0.f, 0.f};
#pragma unroll
    for (int t = 0; t < 4; t++) {
#pragma unroll
      for (int i = 0; i < 4; i++) {
        int rl = 16 * w + quad * 4 + i;
        int cl = 16 * t + lb;
        int c = rl - cl + 63;
        float s = accS[t][i] + b2f(sGqT[c][rl]) + b2f(sGkT[c][cl]);
        float e = fexp2(s * C2);
        pr[t][i] = e;
        rsum[i] += e;
      }
    }
#pragma unroll
    for (int i = 0; i < 4; i++) l_i[i] += rsum16(rsum[i]);

    // probs -> sK overlay (own-wave rows only)
#pragma unroll
    for (int t = 0; t < 4; t++)
#pragma unroll
      for (int i = 0; i < 4; i++)
        sK[16 * w + quad * 4 + i][16 * t + lb] = f2b(pr[t][i]);

    // --- PV ---
    bf16x8 ap0 = ldb8(&sK[row][quad * 8]);
    bf16x8 ap1 = ldb8(&sK[row][32 + quad * 8]);
#pragma unroll
    for (int t = 0; t < 4; t++) {
      int n = 16 * t + lb;
      int sw = (n >> 3) & 7;
      bf16x8 v0 = ldb8(&sVt[n][(quad ^ sw) << 3]);
      bf16x8 v1 = ldb8(&sVt[n][((4 + quad) ^ sw) << 3]);
      accO[t] = MFMA16(ap0, v0, accO[t]);
      accO[t] = MFMA16(ap1, v1, accO[t]);
    }
    __syncthreads();  // barrier C
  }

  u16* Cb = ctx + (size_t)(b * S) * E + h * 64;
#pragma unroll
  for (int t = 0; t < 4; t++)
#pragma unroll
    for (int i = 0; i < 4; i++) {
      int rl = 16 * w + quad * 4 + i;
      Cb[(size_t)(q0 + rl) * E + 16 * t + lb] = f2b(accO[t][i] / l_i[i]);
    }
}

// ---------------------------------------------------------------------------
// Row LayerNorm: fp32 in [8192,1024], fp32 out.
// ---------------------------------------------------------------------------
__global__ __launch_bounds__(256) void lnorm(
    const float* __restrict__ Hp, const float* __restrict__ gamma,
    const float* __restrict__ beta, float* __restrict__ out) {
  __shared__ float red[8];
  const int rowb = blockIdx.x, tid = threadIdx.x;
  const float* hr = Hp + (size_t)rowb * 1024;
  f32x4 v = *(const f32x4*)&hr[tid * 4];
  float s = v.x + v.y + v.z + v.w;
  float q = v.x * v.x + v.y * v.y + v.z * v.z + v.w * v.w;
#pragma unroll
  for (int d = 1; d < 64; d <<= 1) {
    s += __shfl_xor(s, d, 64);
    q += __shfl_xor(q, d, 64);
  }
  int w = tid >> 6, lane = tid & 63;
  if (lane == 0) { red[w] = s; red[4 + w] = q; }
  __syncthreads();
  s = red[0] + red[1] + red[2] + red[3];
  q = red[4] + red[5] + red[6] + red[7];
  float mu = s * (1.f / 1024.f);
  float var = q * (1.f / 1024.f) - mu * mu;
  float rstd = rsqrtf(var + 1e-12f);
  float* orow = out + (size_t)rowb * 1024;
  f32x4 o;
#pragma unroll
  for (int j = 0; j < 4; j++) {
    int c = tid * 4 + j;
    o[j] = (v[j] - mu) * rstd * gamma[c] + beta[c];
  }
  *(f32x4*)&orow[tid * 4] = o;
}

// ---------------------------------------------------------------------------
extern "C" void kernel_launch(void* const* d_in, const int* in_sizes, int n_in,
                              void* d_out, int out_size, void* d_ws,
                              size_t ws_size, hipStream_t stream) {
  const float* X    = (const float*)d_in[0];
  const float* Wq   = (const float*)d_in[1];
  const float* bq   = (const float*)d_in[2];
  const float* Wk   = (const float*)d_in[3];
  const float* bk   = (const float*)d_in[4];
  const float* Wv   = (const float*)d_in[5];
  const float* bv   = (const float*)d_in[6];
  const float* dist = (const float*)d_in[7];
  const float* Wo   = (const float*)d_in[8];
  const float* bo   = (const float*)d_in[9];
  const float* gam  = (const float*)d_in[10];
  const float* bet  = (const float*)d_in[11];

  const size_t NE = (size_t)8192 * 1024;
  char* ws = (char*)d_ws;
  u16* Qw = (u16*)(ws);
  u16* Kw = (u16*)(ws + 2 * NE);
  u16* Vw = (u16*)(ws + 4 * NE);
  u16* Cw = (u16*)(ws + 6 * NE);
  float* Hp = (float*)ws;  // fp32 pre-LN, overlays dead Q+K

  // d_out (33.5 MB fp32) as scratch until the final lnorm overwrites it:
  // Wt* bf16 (4 x 2 MB) + Xb bf16 (16.7 MB)
  char* ob = (char*)d_out;
  u16* Wtq = (u16*)(ob);
  u16* Wtk = (u16*)(ob + (2u << 20));
  u16* Wtv = (u16*)(ob + (4u << 20));
  u16* Wto = (u16*)(ob + (6u << 20));
  u16* Xb  = (u16*)(ob + (8u << 20));

  dim3 bb(256);
  dim3 gw(16, 16);
  convWt<<<gw, bb, 0, stream>>>(Wq, Wtq);
  convWt<<<gw, bb, 0, stream>>>(Wk, Wtk);
  convWt<<<gw, bb, 0, stream>>>(Wv, Wtv);
  convWt<<<gw, bb, 0, stream>>>(Wo, Wto);
  convX<<<dim3(4096), bb, 0, stream>>>(X, Xb);

  dim3 gg(16, 64);
  gemm_bb<0, 0><<<gg, bb, 0, stream>>>(Xb, Wtq, bq, nullptr, nullptr, Qw, 8192, 1024, 1024);
  gemm_bb<0, 0><<<gg, bb, 0, stream>>>(Xb, Wtk, bk, nullptr, nullptr, Kw, 8192, 1024, 1024);
  gemm_bb<0, 0><<<gg, bb, 0, stream>>>(Xb, Wtv, bv, nullptr, nullptr, Vw, 8192, 1024, 1024);
  attn<<<dim3(16, 128), bb, 0, stream>>>(Qw, Kw, Vw, dist, Cw);
  gemm_bb<1, 1><<<gg, bb, 0, stream>>>(Cw, Wto, bo, X, Hp, nullptr, 8192, 1024, 1024);
  lnorm<<<dim3(8192), bb, 0, stream>>>(Hp, gam, bet, (float*)d_out);
}